// Round 14
// baseline (523.536 us; speedup 1.0000x reference)
//
#include <hip/hip_runtime.h>
#include <math.h>

#define L 2048
#define DK 766
#define DKP 768
#define NBH 8
#define NR (NBH * L)
#define NEGV -1000000000.0f

typedef __attribute__((ext_vector_type(8))) short bf16x8_t;
typedef __attribute__((ext_vector_type(4))) float f32x4_t;

#define LDT 72

typedef __attribute__((address_space(1))) const unsigned int gu32;
typedef __attribute__((address_space(3))) unsigned int lu32;

__device__ __forceinline__ short f2bf(float x) {
    union { float f; unsigned u; } v;
    v.f = x;
    unsigned r = v.u + 0x7fff + ((v.u >> 16) & 1);
    return (short)(r >> 16);
}

__device__ __forceinline__ float bf2f(short s) {
    union { unsigned u; float f; } v;
    v.u = ((unsigned)(unsigned short)s) << 16;
    return v.f;
}

__device__ __forceinline__ void gl_lds16(const void* g, void* l) {
    __builtin_amdgcn_global_load_lds((gu32*)g, (lu32*)l, 16, 0, 0);
}

#define BARR() asm volatile("s_barrier" ::: "memory")
#define VMW() asm volatile("s_waitcnt vmcnt(0)" ::: "memory")
#define PRIO1() __builtin_amdgcn_s_setprio(1)
#define PRIO0() __builtin_amdgcn_s_setprio(0)

// -------------------- k_cvtT: fp32 -> bf16 row-major [L][DKP] + transposed [DKP][L] --
__global__ __launch_bounds__(256) void k_cvtT(const float* __restrict__ Q,
                                              const float* __restrict__ K,
                                              short* __restrict__ Qb,
                                              short* __restrict__ Kb,
                                              short* __restrict__ Qt,
                                              short* __restrict__ Kt) {
    __shared__ short T[64 * LDT];
    const int tz = blockIdx.z;
    const int bh = tz & 7;
    const float* X = (tz < 8) ? Q : K;
    short* Xb = (tz < 8) ? Qb : Kb;
    short* Xt = (tz < 8) ? Qt : Kt;
    X += (size_t)bh * L * DK;
    Xb += (size_t)bh * L * DKP;
    Xt += (size_t)bh * DKP * L;
    const int r0 = blockIdx.y * 64, c0 = blockIdx.x * 64;
    const int t = threadIdx.x;
    const int rl = t >> 2, cc = (t & 3) * 16;

    bf16x8_t v0, v1;
#pragma unroll
    for (int p = 0; p < 8; ++p) {
        int c = c0 + cc + 2 * p;
        float2 f = (c < DK) ? *(const float2*)&X[(size_t)(r0 + rl) * DK + c]
                            : make_float2(0.f, 0.f);
        if (p < 4) { v0[2 * p] = f2bf(f.x); v0[2 * p + 1] = f2bf(f.y); }
        else { v1[2 * (p - 4)] = f2bf(f.x); v1[2 * (p - 4) + 1] = f2bf(f.y); }
    }
    *(bf16x8_t*)&Xb[(size_t)(r0 + rl) * DKP + c0 + cc] = v0;
    *(bf16x8_t*)&Xb[(size_t)(r0 + rl) * DKP + c0 + cc + 8] = v1;
    *(bf16x8_t*)&T[rl * LDT + cc] = v0;
    *(bf16x8_t*)&T[rl * LDT + cc + 8] = v1;
    __syncthreads();
    bf16x8_t w0, w1;
#pragma unroll
    for (int p = 0; p < 8; ++p) {
        w0[p] = T[(cc + p) * LDT + rl];
        w1[p] = T[(cc + 8 + p) * LDT + rl];
    }
    *(bf16x8_t*)&Xt[(size_t)(c0 + rl) * L + r0 + cc] = w0;
    *(bf16x8_t*)&Xt[(size_t)(c0 + rl) * L + r0 + cc + 8] = w1;
}

// -------------------- k_score8: 8-phase 256x256, TWO q-panels per block --------------
// Panel 1's tile-0 staging is issued during panel 0's last K-tile and flies under
// the panel-0 epilogue (mask+exp stats) -> its prologue drain is free.
__global__ __launch_bounds__(512, 2) void k_score8(const short* __restrict__ Kb,
                                                   const short* __restrict__ Qb,
                                                   const int* __restrict__ mask,
                                                   short* __restrict__ Sb,
                                                   float* __restrict__ prowM,
                                                   float* __restrict__ prowS,
                                                   float* __restrict__ pcolM,
                                                   float* __restrict__ pcolS) {
    __shared__ __align__(16) short LB[65536];  // A: [0,32768), B: [32768,65536) shorts

    int flat = blockIdx.x;                    // 256 blocks
    int nw = (flat & 7) * 32 + (flat >> 3);   // XCD-chunked bijective swizzle
    int bh = nw >> 5, rem = nw & 31;
    int byp = rem >> 2, bxq = rem & 3;        // byp: k panel, bxq: q panel-PAIR
    const short* Am = Kb + (size_t)bh * L * DKP;
    const short* Bm = Qb + (size_t)bh * L * DKP;
    const int* Mm = mask + (size_t)bh * L * L;
    short* Sm = Sb + (size_t)bh * L * L;
    const int m0 = byp * 256;

    const int t = threadIdx.x, lane = t & 63, wid = t >> 6;
    const int wr = wid >> 2, wc = wid & 3;
    const int lr = lane & 15, lg = lane >> 4;

    const int schunk = (lane & 7) ^ (lane >> 3);
    const short* aSrc = Am + (size_t)(m0 + wid * 8 + (lane >> 3)) * DKP + schunk * 8;
    const short* bSrc0 =
        Bm + (size_t)(bxq * 512 + wid * 8 + (lane >> 3)) * DKP + schunk * 8;
    char* ldsA = (char*)LB;
    char* ldsB = (char*)LB + 65536;

#define STAGEAp(P, cb, k0n)                                                             \
    do {                                                                                \
        gl_lds16((P) + (k0n), ldsA + (cb)*32768 + wid * 1024);                          \
        gl_lds16((P) + (size_t)64 * DKP + (k0n), ldsA + (cb)*32768 + 8192 + wid * 1024);   \
        gl_lds16((P) + (size_t)128 * DKP + (k0n), ldsA + (cb)*32768 + 16384 + wid * 1024); \
        gl_lds16((P) + (size_t)192 * DKP + (k0n), ldsA + (cb)*32768 + 24576 + wid * 1024); \
    } while (0)
#define STAGEBp(P, cb, k0n)                                                             \
    do {                                                                                \
        gl_lds16((P) + (k0n), ldsB + (cb)*32768 + wid * 1024);                          \
        gl_lds16((P) + (size_t)64 * DKP + (k0n), ldsB + (cb)*32768 + 8192 + wid * 1024);   \
        gl_lds16((P) + (size_t)128 * DKP + (k0n), ldsB + (cb)*32768 + 16384 + wid * 1024); \
        gl_lds16((P) + (size_t)192 * DKP + (k0n), ldsB + (cb)*32768 + 24576 + wid * 1024); \
    } while (0)

    const int axr = lr & 7;
    const int kc0 = ((0 + lg) ^ axr) * 8;
    const int kc1 = ((4 + lg) ^ axr) * 8;
    const int aRd = wr * 8192 + lr * 64;
    const int bRd = 32768 + (wc >> 1) * 8192 + ((wc & 1) * 64 + lr) * 64;

#define LDA0(c, i) (*(const bf16x8_t*)&LB[(c)*16384 + aRd + (i)*1024 + kc0])
#define LDA1(c, i) (*(const bf16x8_t*)&LB[(c)*16384 + aRd + (i)*1024 + kc1])
#define LDB0(c, j) (*(const bf16x8_t*)&LB[(c)*16384 + bRd + (j)*1024 + kc0])
#define LDB1(c, j) (*(const bf16x8_t*)&LB[(c)*16384 + bRd + (j)*1024 + kc1])

    f32x4_t acc[8][4];
    bf16x8_t bfr[4][2];

#define PHASE(c, i0, EXTRA)                                                             \
    do {                                                                                \
        bf16x8_t a00 = LDA0(c, i0), a01 = LDA1(c, i0);                                  \
        bf16x8_t a10 = LDA0(c, (i0) + 1), a11 = LDA1(c, (i0) + 1);                      \
        EXTRA;                                                                          \
        BARR();                                                                         \
        PRIO1();                                                                        \
        _Pragma("unroll") for (int j = 0; j < 4; ++j) {                                 \
            acc[i0][j] = __builtin_amdgcn_mfma_f32_16x16x32_bf16(a00, bfr[j][0],        \
                                                                 acc[i0][j], 0, 0, 0);  \
            acc[i0][j] = __builtin_amdgcn_mfma_f32_16x16x32_bf16(a01, bfr[j][1],        \
                                                                 acc[i0][j], 0, 0, 0);  \
            acc[(i0) + 1][j] = __builtin_amdgcn_mfma_f32_16x16x32_bf16(                 \
                a10, bfr[j][0], acc[(i0) + 1][j], 0, 0, 0);                             \
            acc[(i0) + 1][j] = __builtin_amdgcn_mfma_f32_16x16x32_bf16(                 \
                a11, bfr[j][1], acc[(i0) + 1][j], 0, 0, 0);                             \
        }                                                                               \
        PRIO0();                                                                        \
    } while (0)

    const int NT = DKP / 64;  // 12

    for (int pp = 0; pp < 2; ++pp) {
        const int bxp = bxq * 2 + pp;     // q panel index 0..7
        const int n0 = bxp * 256;
        const short* bSrc = bSrc0 + (size_t)pp * 256 * DKP;
        const short* bSrcN = bSrc0 + (size_t)256 * DKP;  // next panel (pp==0 only)

#pragma unroll
        for (int i = 0; i < 8; ++i)
#pragma unroll
            for (int j = 0; j < 4; ++j) acc[i][j] = f32x4_t{0.f, 0.f, 0.f, 0.f};

        if (pp == 0) {
            STAGEAp(aSrc, 0, 0);
            STAGEBp(bSrc, 0, 0);
        }
        // pp==1: tile 0 was staged during pp==0's last K-tile; loads flew
        // through the whole pp==0 epilogue.
        VMW();
        BARR();

        for (int kt = 0; kt < NT - 1; ++kt) {
            const int c = kt & 1;
            const int k0n = (kt + 1) * 64;
#pragma unroll
            for (int j = 0; j < 4; ++j) {
                bfr[j][0] = LDB0(c, j);
                bfr[j][1] = LDB1(c, j);
            }
            PHASE(c, 0, STAGEAp(aSrc, c ^ 1, k0n));
            BARR();
            PHASE(c, 2, STAGEBp(bSrc, c ^ 1, k0n));
            BARR();
            PHASE(c, 4, ((void)0));
            BARR();
            PHASE(c, 6, ((void)0));
            VMW();
            BARR();
        }
        // kt = NT-1 = 11 (c = 1): no drain; pp==0 stages panel 1's tile 0 into buf 0
        {
            const int c = 1;
#pragma unroll
            for (int j = 0; j < 4; ++j) {
                bfr[j][0] = LDB0(c, j);
                bfr[j][1] = LDB1(c, j);
            }
            PHASE(c, 0, if (pp == 0) STAGEAp(aSrc, 0, 0));
            BARR();
            PHASE(c, 2, if (pp == 0) STAGEBp(bSrcN, 0, 0));
            BARR();
            PHASE(c, 4, ((void)0));
            BARR();
            PHASE(c, 6, ((void)0));
            BARR();
        }

        // ---- epilogue: mask + scale + bf16 store; stats from masked f32 acc ----
        const float scale = 1.0f / sqrtf((float)DK);
#pragma unroll
        for (int i = 0; i < 8; ++i) {
            int krow = m0 + wr * 128 + i * 16 + lg * 4;
#pragma unroll
            for (int j = 0; j < 4; ++j) {
                int qcol = n0 + wc * 64 + j * 16 + lr;
#pragma unroll
                for (int r = 0; r < 4; ++r) {
                    int mv = Mm[(size_t)(krow + r) * L + qcol];
                    float v = mv ? NEGV : acc[i][j][r] * scale;
                    acc[i][j][r] = v;
                    Sm[(size_t)(krow + r) * L + qcol] = f2bf(v);
                }
            }
        }

        __syncthreads();  // all waves done with MFMA reads of buf1
        // redb in A-buf1 region (shorts [16384,32768)): buf0 holds panel-1 data
        // in flight (pp==0); 3072 floats = 12 KB <= 32 KB.
        float* redb = (float*)&LB[16384];

#pragma unroll
        for (int i = 0; i < 8; ++i) {
#pragma unroll
            for (int r = 0; r < 4; ++r) {
                float rm = fmaxf(fmaxf(acc[i][0][r], acc[i][1][r]),
                                 fmaxf(acc[i][2][r], acc[i][3][r]));
#pragma unroll
                for (int m = 1; m < 16; m <<= 1) rm = fmaxf(rm, __shfl_xor(rm, m, 64));
                float rs = 0.f;
#pragma unroll
                for (int j = 0; j < 4; ++j) rs += expf(acc[i][j][r] - rm);
#pragma unroll
                for (int m = 1; m < 16; m <<= 1) rs += __shfl_xor(rs, m, 64);
                if (lr == 0) {
                    int kr = wr * 128 + i * 16 + lg * 4 + r;  // 0..255
                    redb[wc * 256 + kr] = rm;
                    redb[1024 + wc * 256 + kr] = rs;
                }
            }
        }
#pragma unroll
        for (int j = 0; j < 4; ++j) {
            float cm = -INFINITY;
#pragma unroll
            for (int i = 0; i < 8; ++i)
#pragma unroll
                for (int r = 0; r < 4; ++r) cm = fmaxf(cm, acc[i][j][r]);
            cm = fmaxf(cm, __shfl_xor(cm, 16, 64));
            cm = fmaxf(cm, __shfl_xor(cm, 32, 64));
            float cs = 0.f;
#pragma unroll
            for (int i = 0; i < 8; ++i)
#pragma unroll
                for (int r = 0; r < 4; ++r) cs += expf(acc[i][j][r] - cm);
            cs += __shfl_xor(cs, 16, 64);
            cs += __shfl_xor(cs, 32, 64);
            if (lg == 0) {
                int qc = wc * 64 + j * 16 + lr;  // 0..255
                redb[2048 + wr * 256 + qc] = cm;
                redb[2560 + wr * 256 + qc] = cs;
            }
        }
        __syncthreads();
        if (t < 256) {
            float m = redb[t];
            float s = 0.f;
#pragma unroll
            for (int w = 1; w < 4; ++w) m = fmaxf(m, redb[w * 256 + t]);
#pragma unroll
            for (int w = 0; w < 4; ++w)
                s += redb[1024 + w * 256 + t] * expf(redb[w * 256 + t] - m);
            size_t o = (size_t)bxp * NR + bh * L + m0 + t;
            prowM[o] = m;
            prowS[o] = s;
        } else {
            int qc = t - 256;
            float mA = redb[2048 + qc], mB = redb[2048 + 256 + qc];
            float sA = redb[2560 + qc], sB = redb[2560 + 256 + qc];
            float m = fmaxf(mA, mB);
            float s = sA * expf(mA - m) + sB * expf(mB - m);
            size_t o = (size_t)byp * NR + bh * L + n0 + qc;
            pcolM[o] = m;
            pcolS[o] = s;
        }
    }
#undef PHASE
#undef STAGEAp
#undef STAGEBp
#undef LDA0
#undef LDA1
#undef LDB0
#undef LDB1
}

// -------------------- k_comb8: merge 8 panel partials -> (max, 1/sum) ---------------
__global__ __launch_bounds__(256) void k_comb8(const float* __restrict__ prowM,
                                               const float* __restrict__ prowS,
                                               const float* __restrict__ pcolM,
                                               const float* __restrict__ pcolS,
                                               float* __restrict__ m1,
                                               float* __restrict__ r1,
                                               float* __restrict__ m2,
                                               float* __restrict__ r2) {
    int idx = blockIdx.x * 256 + threadIdx.x;
    float m = -INFINITY;
#pragma unroll
    for (int c = 0; c < 8; ++c) m = fmaxf(m, prowM[(size_t)c * NR + idx]);
    float s = 0.f;
#pragma unroll
    for (int c = 0; c < 8; ++c)
        s += prowS[(size_t)c * NR + idx] * expf(prowM[(size_t)c * NR + idx] - m);
    m2[idx] = m;
    r2[idx] = 1.0f / s;

    m = -INFINITY;
#pragma unroll
    for (int c = 0; c < 8; ++c) m = fmaxf(m, pcolM[(size_t)c * NR + idx]);
    s = 0.f;
#pragma unroll
    for (int c = 0; c < 8; ++c)
        s += pcolS[(size_t)c * NR + idx] * expf(pcolM[(size_t)c * NR + idx] - m);
    m1[idx] = m;
    r1[idx] = 1.0f / s;
}

// -------------------- k_apply: S in bf16; dual softmax out f32 + bf16 ---------------
__global__ __launch_bounds__(256) void k_apply(const short* __restrict__ Sb,
                                               const float* __restrict__ mr,
                                               const float* __restrict__ rr,
                                               const float* __restrict__ mc,
                                               const float* __restrict__ rc,
                                               float* __restrict__ OutIn,
                                               float* __restrict__ OutTr,
                                               short* __restrict__ bIn,
                                               short* __restrict__ bTr) {
    __shared__ float T[64][65];
    const int bh = blockIdx.z;
    const int rb0 = blockIdx.x * 64, cb0 = blockIdx.y * 64;
    const short* Sm = Sb + (size_t)bh * L * L;
    float* Oin = OutIn + (size_t)bh * L * L;
    float* Otr = OutTr + (size_t)bh * L * L;
    const int t = threadIdx.x, tx = t & 15, ty = t >> 4;

    float4 mcv = *(const float4*)&mc[bh * L + cb0 + tx * 4];
    float4 rcv = *(const float4*)&rc[bh * L + cb0 + tx * 4];

#pragma unroll
    for (int i = 0; i < 4; ++i) {
        int r = rb0 + ty * 4 + i;
        float mrv = mr[bh * L + r], rrv = rr[bh * L + r];
        short4 sx = *(const short4*)&Sm[(size_t)r * L + cb0 + tx * 4];
        float x0 = bf2f(sx.x), x1 = bf2f(sx.y), x2 = bf2f(sx.z), x3 = bf2f(sx.w);
        float4 e = make_float4(expf(x0 - mrv) * rrv, expf(x1 - mrv) * rrv,
                               expf(x2 - mrv) * rrv, expf(x3 - mrv) * rrv);
        *(float4*)&Oin[(size_t)r * L + cb0 + tx * 4] = e;
        short4 b = make_short4(f2bf(e.x), f2bf(e.y), f2bf(e.z), f2bf(e.w));
        *(short4*)&bIn[(size_t)bh * L * L + (size_t)r * L + cb0 + tx * 4] = b;
        T[tx * 4 + 0][ty * 4 + i] = expf(x0 - mcv.x) * rcv.x;
        T[tx * 4 + 1][ty * 4 + i] = expf(x1 - mcv.y) * rcv.y;
        T[tx * 4 + 2][ty * 4 + i] = expf(x2 - mcv.z) * rcv.z;
        T[tx * 4 + 3][ty * 4 + i] = expf(x3 - mcv.w) * rcv.w;
    }
    __syncthreads();
#pragma unroll
    for (int i = 0; i < 4; ++i) {
        int c = ty * 4 + i;
        float4 v = make_float4(T[c][tx * 4], T[c][tx * 4 + 1], T[c][tx * 4 + 2],
                               T[c][tx * 4 + 3]);
        *(float4*)&Otr[(size_t)(cb0 + c) * L + rb0 + tx * 4] = v;
        short4 b = make_short4(f2bf(v.x), f2bf(v.y), f2bf(v.z), f2bf(v.w));
        *(short4*)&bTr[(size_t)bh * L * L + (size_t)(cb0 + c) * L + rb0 + tx * 4] = b;
    }
}

// -------------------- k_ctx8: 8-phase 256x192 fused context GEMMs -------------------
__global__ __launch_bounds__(512, 2) void k_ctx8(const short* __restrict__ a1b,
                                                 const short* __restrict__ a2b,
                                                 const short* __restrict__ Kt,
                                                 const short* __restrict__ Qt,
                                                 float* __restrict__ c1,
                                                 float* __restrict__ c2) {
    __shared__ __align__(16) short LB[57344];

    int flat = blockIdx.x;
    int nw = (flat & 7) * 64 + (flat >> 3);
    int inst = nw >> 5, rem = nw & 31;
    int myp = rem >> 2, nxp = rem & 3;
    int bh = inst & 7;
    const short* Am = ((inst < 8) ? a1b : a2b) + (size_t)bh * L * L;
    const short* Bt = ((inst < 8) ? Kt : Qt) + (size_t)bh * DKP * L;
    float* Cm = ((inst < 8) ? c1 : c2) + (size_t)bh * L * DK;
    const int m0 = myp * 256, n0 = nxp * 192;

    const int t = threadIdx.x, lane = t & 63, wid = t >> 6;
    const int wr = wid >> 2, wc = wid & 3;
    const int lr = lane & 15, lg = lane >> 4;

    const int schunk = (lane & 7) ^ (lane >> 3);
    const short* aSrc = Am + (size_t)(m0 + wid * 8 + (lane >> 3)) * L + schunk * 8;
    const short* bSrc = Bt + (size_t)(n0 + wid * 8 + (lane >> 3)) * L + schunk * 8;
    char* ldsA = (char*)LB;
    char* ldsB = (char*)LB + 65536;

#define STAGEA(cb, k0n)                                                               \
    do {                                                                              \
        gl_lds16(aSrc + (k0n), ldsA + (cb)*32768 + wid * 1024);                       \
        gl_lds16(aSrc + (size_t)64 * L + (k0n), ldsA + (cb)*32768 + 8192 + wid * 1024); \
        gl_lds16(aSrc + (size_t)128 * L + (k0n), ldsA + (cb)*32768 + 16384 + wid * 1024); \
        gl_lds16(aSrc + (size_t)192 * L + (k0n), ldsA + (cb)*32768 + 24576 + wid * 1024); \
    } while (0)
#define STAGEB(cb, k0n)                                                               \
    do {                                                                              \
        gl_lds16(bSrc + (k0n), ldsB + (cb)*24576 + wid * 1024);                       \
        gl_lds16(bSrc + (size_t)64 * L + (k0n), ldsB + (cb)*24576 + 8192 + wid * 1024); \
        gl_lds16(bSrc + (size_t)128 * L + (k0n), ldsB + (cb)*24576 + 16384 + wid * 1024); \
    } while (0)

    const int axr = lr & 7;
    const int kc0 = ((0 + lg) ^ axr) * 8;
    const int kc1 = ((4 + lg) ^ axr) * 8;
    const int aRd = wr * 8192 + lr * 64;
    const int bRd = 32768 + (wc * 48 + lr) * 64;

#define LDA0(c, i) (*(const bf16x8_t*)&LB[(c)*16384 + aRd + (i)*1024 + kc0])
#define LDA1(c, i) (*(const bf16x8_t*)&LB[(c)*16384 + aRd + (i)*1024 + kc1])
#define LDB0(c, j) (*(const bf16x8_t*)&LB[bRd + (c)*12288 + (j)*1024 + kc0])
#define LDB1(c, j) (*(const bf16x8_t*)&LB[bRd + (c)*12288 + (j)*1024 + kc1])

    f32x4_t acc[8][3];
#pragma unroll
    for (int i = 0; i < 8; ++i)
#pragma unroll
        for (int j = 0; j < 3; ++j) acc[i][j] = f32x4_t{0.f, 0.f, 0.f, 0.f};

    bf16x8_t bfr[3][2];

#define PHASE(c, i0, EXTRA)                                                           \
    do {                                                                              \
        bf16x8_t a00 = LDA0(c, i0), a01 = LDA1(c, i0);                                \
        bf16x8_t a10 = LDA0(c, (i0) + 1), a11 = LDA1(c, (i0) + 1);                    \
        EXTRA;                                                                        \
        BARR();                                                                       \
        PRIO1();                                                                      \
        _Pragma("unroll") for (int j = 0; j < 3; ++j) {                               \
            acc[i0][j] = __builtin_amdgcn_mfma_f32_16x16x32_bf16(a00, bfr[j][0],      \
                                                                 acc[i0][j], 0, 0, 0); \
            acc[i0][j] = __builtin_amdgcn_mfma_f32_16x16x32_bf16(a01, bfr[j][1],      \
                                                                 acc[i0][j], 0, 0, 0); \
            acc[(i0) + 1][j] = __builtin_amdgcn_mfma_f32_16x16x32_bf16(               \
                a10, bfr[j][0], acc[(i0) + 1][j], 0, 0, 0);                           \
            acc[(i0) + 1][j] = __builtin_amdgcn_mfma_f32_16x16x32_bf16(               \
                a11, bfr[j][1], acc[(i0) + 1][j], 0, 0, 0);                           \
        }                                                                             \
        PRIO0();                                                                      \
    } while (0)

    const int NT = L / 64;  // 32
    STAGEA(0, 0);
    STAGEB(0, 0);
    VMW();
    BARR();

    for (int kt = 0; kt < NT; ++kt) {
        const int c = kt & 1;
        const bool ds = (kt + 1 < NT);
        const int k0n = (kt + 1) * 64;
#pragma unroll
        for (int j = 0; j < 3; ++j) {
            bfr[j][0] = LDB0(c, j);
            bfr[j][1] = LDB1(c, j);
        }
        PHASE(c, 0, if (ds) STAGEA(c ^ 1, k0n));
        BARR();
        PHASE(c, 2, if (ds) STAGEB(c ^ 1, k0n));
        BARR();
        PHASE(c, 4, ((void)0));
        BARR();
        PHASE(c, 6, ((void)0));
        if (ds) VMW();
        BARR();
    }

#pragma unroll
    for (int i = 0; i < 8; ++i) {
        int row = m0 + wr * 128 + i * 16 + lg * 4;
#pragma unroll
        for (int j = 0; j < 3; ++j) {
            int col = n0 + wc * 48 + j * 16 + lr;
            if (col < DK) {
#pragma unroll
                for (int r = 0; r < 4; ++r)
                    Cm[(size_t)(row + r) * DK + col] = acc[i][j][r];
            }
        }
    }
#undef PHASE
#undef STAGEA
#undef STAGEB
#undef LDA0
#undef LDA1
#undef LDB0
#undef LDB1
}

extern "C" void kernel_launch(void* const* d_in, const int* in_sizes, int n_in,
                              void* d_out, int out_size, void* d_ws, size_t ws_size,
                              hipStream_t stream) {
    const float* Q = (const float*)d_in[0];
    const float* K = (const float*)d_in[1];
    const int* mask = (const int*)d_in[2];
    float* out = (float*)d_out;

    const size_t CTX = (size_t)NBH * L * DK;
    const size_t ATT = (size_t)NBH * L * L;
    float* c1 = out;
    float* c2 = out + CTX;
    float* a1 = out + 2 * CTX;
    float* a2 = out + 2 * CTX + ATT;

    float* ws = (float*)d_ws;
    float* m1 = ws;
    float* r1 = ws + NR;
    float* m2 = ws + 2 * (size_t)NR;
    float* r2 = ws + 3 * (size_t)NR;
    const size_t QBE = (size_t)NBH * L * DKP;
    short* Qb = (short*)(ws + 4 * (size_t)NR);
    short* Kb = Qb + QBE;
    short* a1b = Kb + QBE;
    short* a2b = a1b + ATT;
    short* Qt = a2b + ATT;
    short* Kt = Qt + QBE;

    float* prowM = c1;
    float* prowS = c1 + 8 * (size_t)NR;
    float* pcolM = c1 + 16 * (size_t)NR;
    float* pcolS = c1 + 24 * (size_t)NR;

    dim3 blk(256);

    k_cvtT<<<dim3(12, 32, 16), blk, 0, stream>>>(Q, K, Qb, Kb, Qt, Kt);
    // Sb (bf16 scores) stored in a2b slot; apply overwrites it with attn2-bf16
    k_score8<<<dim3(256), dim3(512), 0, stream>>>(Kb, Qb, mask, a2b, prowM, prowS,
                                                  pcolM, pcolS);
    k_comb8<<<dim3(NR / 256), blk, 0, stream>>>(prowM, prowS, pcolM, pcolS, m1, r1,
                                                m2, r2);
    k_apply<<<dim3(32, 32, NBH), blk, 0, stream>>>(a2b, m2, r2, m1, r1, a2, a1, a2b,
                                                   a1b);
    k_ctx8<<<dim3(512), dim3(512), 0, stream>>>(a1b, a2b, Kt, Qt, c1, c2);
}

// Round 15
// 410.733 us; speedup vs baseline: 1.2746x; 1.2746x over previous
//
#include <hip/hip_runtime.h>
#include <math.h>

#define L 2048
#define DK 766
#define DKP 768
#define NBH 8
#define NR (NBH * L)
#define NEGV -1000000000.0f

typedef __attribute__((ext_vector_type(8))) short bf16x8_t;
typedef __attribute__((ext_vector_type(4))) float f32x4_t;

#define LDT 72

typedef __attribute__((address_space(1))) const unsigned int gu32;
typedef __attribute__((address_space(3))) unsigned int lu32;

__device__ __forceinline__ short f2bf(float x) {
    union { float f; unsigned u; } v;
    v.f = x;
    unsigned r = v.u + 0x7fff + ((v.u >> 16) & 1);
    return (short)(r >> 16);
}

__device__ __forceinline__ float bf2f(short s) {
    union { unsigned u; float f; } v;
    v.u = ((unsigned)(unsigned short)s) << 16;
    return v.f;
}

__device__ __forceinline__ void gl_lds16(const void* g, void* l) {
    __builtin_amdgcn_global_load_lds((gu32*)g, (lu32*)l, 16, 0, 0);
}

#define BARR() asm volatile("s_barrier" ::: "memory")
#define VMW() asm volatile("s_waitcnt vmcnt(0)" ::: "memory")
#define PRIO1() __builtin_amdgcn_s_setprio(1)
#define PRIO0() __builtin_amdgcn_s_setprio(0)

// -------------------- k_cvtT: fp32 -> bf16 row-major [L][DKP] + transposed [DKP][L] --
__global__ __launch_bounds__(256) void k_cvtT(const float* __restrict__ Q,
                                              const float* __restrict__ K,
                                              short* __restrict__ Qb,
                                              short* __restrict__ Kb,
                                              short* __restrict__ Qt,
                                              short* __restrict__ Kt) {
    __shared__ short T[64 * LDT];
    const int tz = blockIdx.z;
    const int bh = tz & 7;
    const float* X = (tz < 8) ? Q : K;
    short* Xb = (tz < 8) ? Qb : Kb;
    short* Xt = (tz < 8) ? Qt : Kt;
    X += (size_t)bh * L * DK;
    Xb += (size_t)bh * L * DKP;
    Xt += (size_t)bh * DKP * L;
    const int r0 = blockIdx.y * 64, c0 = blockIdx.x * 64;
    const int t = threadIdx.x;
    const int rl = t >> 2, cc = (t & 3) * 16;

    bf16x8_t v0, v1;
#pragma unroll
    for (int p = 0; p < 8; ++p) {
        int c = c0 + cc + 2 * p;
        float2 f = (c < DK) ? *(const float2*)&X[(size_t)(r0 + rl) * DK + c]
                            : make_float2(0.f, 0.f);
        if (p < 4) { v0[2 * p] = f2bf(f.x); v0[2 * p + 1] = f2bf(f.y); }
        else { v1[2 * (p - 4)] = f2bf(f.x); v1[2 * (p - 4) + 1] = f2bf(f.y); }
    }
    *(bf16x8_t*)&Xb[(size_t)(r0 + rl) * DKP + c0 + cc] = v0;
    *(bf16x8_t*)&Xb[(size_t)(r0 + rl) * DKP + c0 + cc + 8] = v1;
    *(bf16x8_t*)&T[rl * LDT + cc] = v0;
    *(bf16x8_t*)&T[rl * LDT + cc + 8] = v1;
    __syncthreads();
    bf16x8_t w0, w1;
#pragma unroll
    for (int p = 0; p < 8; ++p) {
        w0[p] = T[(cc + p) * LDT + rl];
        w1[p] = T[(cc + 8 + p) * LDT + rl];
    }
    *(bf16x8_t*)&Xt[(size_t)(c0 + rl) * L + r0 + cc] = w0;
    *(bf16x8_t*)&Xt[(size_t)(c0 + rl) * L + r0 + cc + 8] = w1;
}

// -------------------- k_score2: 256x128 tile, single-buffer, 2 blocks/CU ------------
// 8 waves (4x2 of 64x64). Sb[k][q]=bf16((K.Q^T)*scale masked) + fused stats partials.
// Mem phases of one block overlap MFMA phases of the co-resident block (m114 TLP).
__global__ __launch_bounds__(512, 4) void k_score2(const short* __restrict__ Kb,
                                                   const short* __restrict__ Qb,
                                                   const int* __restrict__ mask,
                                                   short* __restrict__ Sb,
                                                   float* __restrict__ prowM,
                                                   float* __restrict__ prowS,
                                                   float* __restrict__ pcolM,
                                                   float* __restrict__ pcolS) {
    __shared__ __align__(16) short LB[24576];  // A [256][64] @0, B [128][64] @16384

    int flat = blockIdx.x;                     // 1024 blocks
    int nw = (flat & 7) * 128 + (flat >> 3);   // XCD-chunked bijective swizzle
    int bh = nw >> 7, rem = nw & 127;
    int byp = rem >> 4, bxp = rem & 15;        // byp: k panel (256), bxp: q panel (128)
    const short* Am = Kb + (size_t)bh * L * DKP;
    const short* Bm = Qb + (size_t)bh * L * DKP;
    const int* Mm = mask + (size_t)bh * L * L;
    short* Sm = Sb + (size_t)bh * L * L;
    const int m0 = byp * 256, n0 = bxp * 128;

    const int t = threadIdx.x, lane = t & 63, wid = t >> 6;  // 8 waves
    const int wr = wid >> 1, wc = wid & 1;                   // 4 x 2
    const int lr = lane & 15, lg = lane >> 4;

    // staging sources: pre-swizzled chunk so linear-LDS + swizzled read match
    const int schunk = (lane & 7) ^ (lane >> 3);
    const short* aSrc = Am + (size_t)(m0 + wid * 32 + (lane >> 3)) * DKP + schunk * 8;
    const short* bSrc = Bm + (size_t)(n0 + wid * 16 + (lane >> 3)) * DKP + schunk * 8;
    char* ldsA = (char*)LB;            // row-major [256][64] shorts: row r @ byte r*128
    char* ldsB = (char*)LB + 32768;    // row-major [128][64]

    const int axr = lr & 7;
    const int kc0 = ((0 + lg) ^ axr) * 8;  // ks=0 swizzled chunk (shorts)
    const int kc1 = ((4 + lg) ^ axr) * 8;  // ks=1

    f32x4_t acc[4][4];
#pragma unroll
    for (int i = 0; i < 4; ++i)
#pragma unroll
        for (int j = 0; j < 4; ++j) acc[i][j] = f32x4_t{0.f, 0.f, 0.f, 0.f};

    const int NT = DKP / 64;  // 12
    for (int kt = 0; kt < NT; ++kt) {
        const int k0 = kt * 64;
        // stage A (4x8 rows/wave) + B (2x8 rows/wave), linear LDS dest
#pragma unroll
        for (int g = 0; g < 4; ++g)
            gl_lds16(aSrc + (size_t)(8 * g) * DKP + k0, ldsA + wid * 4096 + g * 1024);
#pragma unroll
        for (int g = 0; g < 2; ++g)
            gl_lds16(bSrc + (size_t)(8 * g) * DKP + k0, ldsB + wid * 2048 + g * 1024);
        VMW();
        BARR();
        PRIO1();
#pragma unroll
        for (int ks = 0; ks < 2; ++ks) {
            const int kc = ks ? kc1 : kc0;
            bf16x8_t av[4], bv[4];
#pragma unroll
            for (int i = 0; i < 4; ++i)
                av[i] = *(const bf16x8_t*)&LB[wr * 4096 + i * 1024 + lr * 64 + kc];
#pragma unroll
            for (int j = 0; j < 4; ++j)
                bv[j] = *(const bf16x8_t*)&LB[16384 + wc * 4096 + j * 1024 + lr * 64 + kc];
#pragma unroll
            for (int i = 0; i < 4; ++i)
#pragma unroll
                for (int j = 0; j < 4; ++j)
                    acc[i][j] = __builtin_amdgcn_mfma_f32_16x16x32_bf16(
                        av[i], bv[j], acc[i][j], 0, 0, 0);
        }
        PRIO0();
        BARR();  // all reads done before next tile's staging lands
    }

    // ---- epilogue: mask + scale + bf16 store; stats from masked f32 acc ----
    const float scale = 1.0f / sqrtf((float)DK);
#pragma unroll
    for (int i = 0; i < 4; ++i) {
        int krow = m0 + wr * 64 + i * 16 + lg * 4;
#pragma unroll
        for (int j = 0; j < 4; ++j) {
            int qcol = n0 + wc * 64 + j * 16 + lr;
#pragma unroll
            for (int r = 0; r < 4; ++r) {
                int mv = Mm[(size_t)(krow + r) * L + qcol];
                float v = mv ? NEGV : acc[i][j][r] * scale;
                acc[i][j][r] = v;
                Sm[(size_t)(krow + r) * L + qcol] = f2bf(v);
            }
        }
    }

    __syncthreads();
    // redb: rowM [2][256]@0  rowS [2][256]@512  colM [4][128]@1024  colS [4][128]@1536
    float* redb = (float*)LB;

    // row partials (fixed k-row, reduce over block's 128 q): j regs + lr lanes
#pragma unroll
    for (int i = 0; i < 4; ++i) {
#pragma unroll
        for (int r = 0; r < 4; ++r) {
            float rm = fmaxf(fmaxf(acc[i][0][r], acc[i][1][r]),
                             fmaxf(acc[i][2][r], acc[i][3][r]));
#pragma unroll
            for (int m = 1; m < 16; m <<= 1) rm = fmaxf(rm, __shfl_xor(rm, m, 64));
            float rs = 0.f;
#pragma unroll
            for (int j = 0; j < 4; ++j) rs += expf(acc[i][j][r] - rm);
#pragma unroll
            for (int m = 1; m < 16; m <<= 1) rs += __shfl_xor(rs, m, 64);
            if (lr == 0) {
                int kr = wr * 64 + i * 16 + lg * 4 + r;  // 0..255
                redb[wc * 256 + kr] = rm;
                redb[512 + wc * 256 + kr] = rs;
            }
        }
    }
    // col partials (fixed q-col, reduce over block's 256 k): i,r regs + lg lanes
#pragma unroll
    for (int j = 0; j < 4; ++j) {
        float cm = -INFINITY;
#pragma unroll
        for (int i = 0; i < 4; ++i)
#pragma unroll
            for (int r = 0; r < 4; ++r) cm = fmaxf(cm, acc[i][j][r]);
        cm = fmaxf(cm, __shfl_xor(cm, 16, 64));
        cm = fmaxf(cm, __shfl_xor(cm, 32, 64));
        float cs = 0.f;
#pragma unroll
        for (int i = 0; i < 4; ++i)
#pragma unroll
            for (int r = 0; r < 4; ++r) cs += expf(acc[i][j][r] - cm);
        cs += __shfl_xor(cs, 16, 64);
        cs += __shfl_xor(cs, 32, 64);
        if (lg == 0) {
            int qc = wc * 64 + j * 16 + lr;  // 0..127
            redb[1024 + wr * 128 + qc] = cm;
            redb[1536 + wr * 128 + qc] = cs;
        }
    }
    __syncthreads();
    if (t < 256) {
        float mA = redb[t], mB = redb[256 + t];
        float sA = redb[512 + t], sB = redb[512 + 256 + t];
        float m = fmaxf(mA, mB);
        float s = sA * expf(mA - m) + sB * expf(mB - m);
        size_t o = (size_t)bxp * NR + bh * L + m0 + t;
        prowM[o] = m;
        prowS[o] = s;
    } else if (t < 384) {
        int qc = t - 256;
        float m = redb[1024 + qc];
#pragma unroll
        for (int w = 1; w < 4; ++w) m = fmaxf(m, redb[1024 + w * 128 + qc]);
        float s = 0.f;
#pragma unroll
        for (int w = 0; w < 4; ++w)
            s += redb[1536 + w * 128 + qc] * expf(redb[1024 + w * 128 + qc] - m);
        size_t o = (size_t)byp * NR + bh * L + n0 + qc;
        pcolM[o] = m;
        pcolS[o] = s;
    }
}

// -------------------- k_comb: merge panel partials -> (max, 1/sum) ------------------
// rows (attn2): 16 q-panels; cols (attn1): 8 k-panels.
__global__ __launch_bounds__(256) void k_comb(const float* __restrict__ prowM,
                                              const float* __restrict__ prowS,
                                              const float* __restrict__ pcolM,
                                              const float* __restrict__ pcolS,
                                              float* __restrict__ m1,
                                              float* __restrict__ r1,
                                              float* __restrict__ m2,
                                              float* __restrict__ r2) {
    int idx = blockIdx.x * 256 + threadIdx.x;
    float m = -INFINITY;
#pragma unroll
    for (int c = 0; c < 16; ++c) m = fmaxf(m, prowM[(size_t)c * NR + idx]);
    float s = 0.f;
#pragma unroll
    for (int c = 0; c < 16; ++c)
        s += prowS[(size_t)c * NR + idx] * expf(prowM[(size_t)c * NR + idx] - m);
    m2[idx] = m;
    r2[idx] = 1.0f / s;

    m = -INFINITY;
#pragma unroll
    for (int c = 0; c < 8; ++c) m = fmaxf(m, pcolM[(size_t)c * NR + idx]);
    s = 0.f;
#pragma unroll
    for (int c = 0; c < 8; ++c)
        s += pcolS[(size_t)c * NR + idx] * expf(pcolM[(size_t)c * NR + idx] - m);
    m1[idx] = m;
    r1[idx] = 1.0f / s;
}

// -------------------- k_apply: S in bf16; dual softmax out f32 + bf16 ---------------
__global__ __launch_bounds__(256) void k_apply(const short* __restrict__ Sb,
                                               const float* __restrict__ mr,
                                               const float* __restrict__ rr,
                                               const float* __restrict__ mc,
                                               const float* __restrict__ rc,
                                               float* __restrict__ OutIn,
                                               float* __restrict__ OutTr,
                                               short* __restrict__ bIn,
                                               short* __restrict__ bTr) {
    __shared__ float T[64][65];
    const int bh = blockIdx.z;
    const int rb0 = blockIdx.x * 64, cb0 = blockIdx.y * 64;
    const short* Sm = Sb + (size_t)bh * L * L;
    float* Oin = OutIn + (size_t)bh * L * L;
    float* Otr = OutTr + (size_t)bh * L * L;
    const int t = threadIdx.x, tx = t & 15, ty = t >> 4;

    float4 mcv = *(const float4*)&mc[bh * L + cb0 + tx * 4];
    float4 rcv = *(const float4*)&rc[bh * L + cb0 + tx * 4];

#pragma unroll
    for (int i = 0; i < 4; ++i) {
        int r = rb0 + ty * 4 + i;
        float mrv = mr[bh * L + r], rrv = rr[bh * L + r];
        short4 sx = *(const short4*)&Sm[(size_t)r * L + cb0 + tx * 4];
        float x0 = bf2f(sx.x), x1 = bf2f(sx.y), x2 = bf2f(sx.z), x3 = bf2f(sx.w);
        float4 e = make_float4(expf(x0 - mrv) * rrv, expf(x1 - mrv) * rrv,
                               expf(x2 - mrv) * rrv, expf(x3 - mrv) * rrv);
        *(float4*)&Oin[(size_t)r * L + cb0 + tx * 4] = e;
        short4 b = make_short4(f2bf(e.x), f2bf(e.y), f2bf(e.z), f2bf(e.w));
        *(short4*)&bIn[(size_t)bh * L * L + (size_t)r * L + cb0 + tx * 4] = b;
        T[tx * 4 + 0][ty * 4 + i] = expf(x0 - mcv.x) * rcv.x;
        T[tx * 4 + 1][ty * 4 + i] = expf(x1 - mcv.y) * rcv.y;
        T[tx * 4 + 2][ty * 4 + i] = expf(x2 - mcv.z) * rcv.z;
        T[tx * 4 + 3][ty * 4 + i] = expf(x3 - mcv.w) * rcv.w;
    }
    __syncthreads();
#pragma unroll
    for (int i = 0; i < 4; ++i) {
        int c = ty * 4 + i;
        float4 v = make_float4(T[c][tx * 4], T[c][tx * 4 + 1], T[c][tx * 4 + 2],
                               T[c][tx * 4 + 3]);
        *(float4*)&Otr[(size_t)(cb0 + c) * L + rb0 + tx * 4] = v;
        short4 b = make_short4(f2bf(v.x), f2bf(v.y), f2bf(v.z), f2bf(v.w));
        *(short4*)&bTr[(size_t)bh * L * L + (size_t)(cb0 + c) * L + rb0 + tx * 4] = b;
    }
}

// -------------------- k_ctx8: 8-phase 256x192 fused context GEMMs -------------------
__global__ __launch_bounds__(512, 2) void k_ctx8(const short* __restrict__ a1b,
                                                 const short* __restrict__ a2b,
                                                 const short* __restrict__ Kt,
                                                 const short* __restrict__ Qt,
                                                 float* __restrict__ c1,
                                                 float* __restrict__ c2) {
    __shared__ __align__(16) short LB[57344];

    int flat = blockIdx.x;
    int nw = (flat & 7) * 64 + (flat >> 3);
    int inst = nw >> 5, rem = nw & 31;
    int myp = rem >> 2, nxp = rem & 3;
    int bh = inst & 7;
    const short* Am = ((inst < 8) ? a1b : a2b) + (size_t)bh * L * L;
    const short* Bt = ((inst < 8) ? Kt : Qt) + (size_t)bh * DKP * L;
    float* Cm = ((inst < 8) ? c1 : c2) + (size_t)bh * L * DK;
    const int m0 = myp * 256, n0 = nxp * 192;

    const int t = threadIdx.x, lane = t & 63, wid = t >> 6;
    const int wr = wid >> 2, wc = wid & 3;
    const int lr = lane & 15, lg = lane >> 4;

    const int schunk = (lane & 7) ^ (lane >> 3);
    const short* aSrc = Am + (size_t)(m0 + wid * 8 + (lane >> 3)) * L + schunk * 8;
    const short* bSrc = Bt + (size_t)(n0 + wid * 8 + (lane >> 3)) * L + schunk * 8;
    char* ldsA = (char*)LB;
    char* ldsB = (char*)LB + 65536;

#define STAGEA(cb, k0n)                                                               \
    do {                                                                              \
        gl_lds16(aSrc + (k0n), ldsA + (cb)*32768 + wid * 1024);                       \
        gl_lds16(aSrc + (size_t)64 * L + (k0n), ldsA + (cb)*32768 + 8192 + wid * 1024); \
        gl_lds16(aSrc + (size_t)128 * L + (k0n), ldsA + (cb)*32768 + 16384 + wid * 1024); \
        gl_lds16(aSrc + (size_t)192 * L + (k0n), ldsA + (cb)*32768 + 24576 + wid * 1024); \
    } while (0)
#define STAGEB(cb, k0n)                                                               \
    do {                                                                              \
        gl_lds16(bSrc + (k0n), ldsB + (cb)*24576 + wid * 1024);                       \
        gl_lds16(bSrc + (size_t)64 * L + (k0n), ldsB + (cb)*24576 + 8192 + wid * 1024); \
        gl_lds16(bSrc + (size_t)128 * L + (k0n), ldsB + (cb)*24576 + 16384 + wid * 1024); \
    } while (0)

    const int axr = lr & 7;
    const int kc0 = ((0 + lg) ^ axr) * 8;
    const int kc1 = ((4 + lg) ^ axr) * 8;
    const int aRd = wr * 8192 + lr * 64;
    const int bRd = 32768 + (wc * 48 + lr) * 64;

#define LDA0(c, i) (*(const bf16x8_t*)&LB[(c)*16384 + aRd + (i)*1024 + kc0])
#define LDA1(c, i) (*(const bf16x8_t*)&LB[(c)*16384 + aRd + (i)*1024 + kc1])
#define LDB0(c, j) (*(const bf16x8_t*)&LB[bRd + (c)*12288 + (j)*1024 + kc0])
#define LDB1(c, j) (*(const bf16x8_t*)&LB[bRd + (c)*12288 + (j)*1024 + kc1])

    f32x4_t acc[8][3];
#pragma unroll
    for (int i = 0; i < 8; ++i)
#pragma unroll
        for (int j = 0; j < 3; ++j) acc[i][j] = f32x4_t{0.f, 0.f, 0.f, 0.f};

    bf16x8_t bfr[3][2];

#define PHASE(c, i0, EXTRA)                                                           \
    do {                                                                              \
        bf16x8_t a00 = LDA0(c, i0), a01 = LDA1(c, i0);                                \
        bf16x8_t a10 = LDA0(c, (i0) + 1), a11 = LDA1(c, (i0) + 1);                    \
        EXTRA;                                                                        \
        BARR();                                                                       \
        PRIO1();                                                                      \
        _Pragma("unroll") for (int j = 0; j < 3; ++j) {                               \
            acc[i0][j] = __builtin_amdgcn_mfma_f32_16x16x32_bf16(a00, bfr[j][0],      \
                                                                 acc[i0][j], 0, 0, 0); \
            acc[i0][j] = __builtin_amdgcn_mfma_f32_16x16x32_bf16(a01, bfr[j][1],      \
                                                                 acc[i0][j], 0, 0, 0); \
            acc[(i0) + 1][j] = __builtin_amdgcn_mfma_f32_16x16x32_bf16(               \
                a10, bfr[j][0], acc[(i0) + 1][j], 0, 0, 0);                           \
            acc[(i0) + 1][j] = __builtin_amdgcn_mfma_f32_16x16x32_bf16(               \
                a11, bfr[j][1], acc[(i0) + 1][j], 0, 0, 0);                           \
        }                                                                             \
        PRIO0();                                                                      \
    } while (0)

    const int NT = L / 64;  // 32
    STAGEA(0, 0);
    STAGEB(0, 0);
    VMW();
    BARR();

    for (int kt = 0; kt < NT; ++kt) {
        const int c = kt & 1;
        const bool ds = (kt + 1 < NT);
        const int k0n = (kt + 1) * 64;
#pragma unroll
        for (int j = 0; j < 3; ++j) {
            bfr[j][0] = LDB0(c, j);
            bfr[j][1] = LDB1(c, j);
        }
        PHASE(c, 0, if (ds) STAGEA(c ^ 1, k0n));
        BARR();
        PHASE(c, 2, if (ds) STAGEB(c ^ 1, k0n));
        BARR();
        PHASE(c, 4, ((void)0));
        BARR();
        PHASE(c, 6, ((void)0));
        if (ds) VMW();
        BARR();
    }

#pragma unroll
    for (int i = 0; i < 8; ++i) {
        int row = m0 + wr * 128 + i * 16 + lg * 4;
#pragma unroll
        for (int j = 0; j < 3; ++j) {
            int col = n0 + wc * 48 + j * 16 + lr;
            if (col < DK) {
#pragma unroll
                for (int r = 0; r < 4; ++r)
                    Cm[(size_t)(row + r) * DK + col] = acc[i][j][r];
            }
        }
    }
#undef PHASE
#undef STAGEA
#undef STAGEB
#undef LDA0
#undef LDA1
#undef LDB0
#undef LDB1
}

extern "C" void kernel_launch(void* const* d_in, const int* in_sizes, int n_in,
                              void* d_out, int out_size, void* d_ws, size_t ws_size,
                              hipStream_t stream) {
    const float* Q = (const float*)d_in[0];
    const float* K = (const float*)d_in[1];
    const int* mask = (const int*)d_in[2];
    float* out = (float*)d_out;

    const size_t CTX = (size_t)NBH * L * DK;
    const size_t ATT = (size_t)NBH * L * L;
    float* c1 = out;
    float* c2 = out + CTX;
    float* a1 = out + 2 * CTX;
    float* a2 = out + 2 * CTX + ATT;

    float* ws = (float*)d_ws;
    float* m1 = ws;
    float* r1 = ws + NR;
    float* m2 = ws + 2 * (size_t)NR;
    float* r2 = ws + 3 * (size_t)NR;
    const size_t QBE = (size_t)NBH * L * DKP;
    short* Qb = (short*)(ws + 4 * (size_t)NR);
    short* Kb = Qb + QBE;
    short* a1b = Kb + QBE;
    short* a2b = a1b + ATT;
    short* Qt = a2b + ATT;
    short* Kt = Qt + QBE;

    // partial stats scratch in c1 output region (overwritten later by ctx8)
    float* prowM = c1;                       // [16][NR]
    float* prowS = c1 + 16 * (size_t)NR;     // [16][NR]
    float* pcolM = c1 + 32 * (size_t)NR;     // [8][NR]
    float* pcolS = c1 + 40 * (size_t)NR;     // [8][NR]

    dim3 blk(256);

    k_cvtT<<<dim3(12, 32, 16), blk, 0, stream>>>(Q, K, Qb, Kb, Qt, Kt);
    // Sb (bf16 scores) stored in a2b slot; apply overwrites it with attn2-bf16
    k_score2<<<dim3(1024), dim3(512), 0, stream>>>(Kb, Qb, mask, a2b, prowM, prowS,
                                                   pcolM, pcolS);
    k_comb<<<dim3(NR / 256), blk, 0, stream>>>(prowM, prowS, pcolM, pcolS, m1, r1,
                                               m2, r2);
    k_apply<<<dim3(32, 32, NBH), blk, 0, stream>>>(a2b, m2, r2, m1, r1, a2, a1, a2b,
                                                   a1b);
    k_ctx8<<<dim3(512), dim3(512), 0, stream>>>(a1b, a2b, Kt, Qt, c1, c2);
}